// Round 9
// baseline (193.829 us; speedup 1.0000x reference)
//
#include <hip/hip_runtime.h>

// Fused 2-layer LSTM (B=4096, T=512, I=H=32) + projection — PLAIN FP16 MFMA, 16 waves.
// Round-9: v8 + lgkm-only step barrier. __syncthreads() emits s_waitcnt vmcnt(0)
// lgkmcnt(0) before s_barrier, force-draining the chunk's prefetched global x-loads at
// the first step-barrier (~700 cyc HBM latency once per 16 steps). Cross-wave LDS
// visibility needs only lgkmcnt(0): h/XA exchange is via LDS; global loads land in
// private VGPRs (compiler inserts its own vmcnt before their use). Single opaque asm
// block {s_waitcnt lgkmcnt(0); s_barrier} with "memory" clobber = nothing crosses.
//
// Structure (v6/v8, proven best): grid 256 x 1024 thr = 16 waves (4/SIMD). Waves 0-7:
// L1 M-tile t=wv (units t*4..t*4+3); waves 8-15: L2 tile t=wv-8. Layer-pipelined:
// iter i = L1 step i + L2 step i-1; 1 barrier/iter. Lane owns ONE cell (unit t*4+(l>>4),
// batch l&15): D regs = (i,f,g,o) -> lane-local update. L1: pX = bias + MFMA(Wi, x(t))
// prefetched a step ahead. L2: e = bias+MFMA(Wi,h1) || f = MFMA(Wr,h2), merged by v_add.
// Fused activations (8 trans/cell): i*g = (1-y)/((1+xi)(1+y)), o*tanh(c) = (1-u)/
// ((1+xo)(1+u)); weights pre-scaled by -log2e (i,f,o) / -2log2e (g); fp32 accumulate.
//
// Buffers: H1 slot i&1 = h1(i); L1 reads H1[(i-1)&1]; L2 reads H1[(i-1)&1] and
// H2[(i-2)&1], writes H2[(i-1)&1]. All cross-iter hazards barrier-separated.
// i=0: L2 commit guarded. Epilogue: L2 computes step 511 from H1[1], H2[0].

typedef __attribute__((ext_vector_type(4))) float f32x4;
typedef _Float16 half8 __attribute__((ext_vector_type(8)));

#define MFMA_F16(a, b, c) __builtin_amdgcn_mfma_f32_16x16x32_f16(a, b, c, 0, 0, 0)
// lgkm-only workgroup barrier: LDS-visibility fence + barrier, NO vmcnt drain.
#define BAR_LGKM() asm volatile("s_waitcnt lgkmcnt(0)\n\ts_barrier" ::: "memory")

namespace {
constexpr int TSTEPS = 512;
constexpr int CT     = 16;
constexpr float LOG2E = 1.4426950408889634f;

// acc = (zi^, zf^, yg^, zo^): pre-scaled preacts (-log2e*z for i,f,o; -2log2e*z for g).
// Fused-rcp gate evaluation; updates c, returns h. 5 exp2 + 3 rcp.
__device__ __forceinline__ float act_fused(const f32x4 acc, float& c) {
    const float xi = __builtin_amdgcn_exp2f(acc[0]);
    const float xf = __builtin_amdgcn_exp2f(acc[1]);
    const float y  = __builtin_amdgcn_exp2f(acc[2]);
    const float xo = __builtin_amdgcn_exp2f(acc[3]);
    const float fv = __builtin_amdgcn_rcpf(1.0f + xf);                       // sigma(zf)
    const float ig = (1.0f - y) * __builtin_amdgcn_rcpf((1.0f + xi) * (1.0f + y));
    const float cc = fmaf(fv, c, ig);
    c = cc;
    const float u  = __builtin_amdgcn_exp2f(cc * (-2.0f * LOG2E));
    return (1.0f - u) * __builtin_amdgcn_rcpf((1.0f + xo) * (1.0f + u));    // o*tanh(c)
}
}  // namespace

__global__ __launch_bounds__(1024, 1)
void lstm2_v9(const float* __restrict__ x,
              const float* __restrict__ Wih1, const float* __restrict__ Whh1,
              const float* __restrict__ bih1, const float* __restrict__ bhh1,
              const float* __restrict__ Wih2, const float* __restrict__ Whh2,
              const float* __restrict__ bih2, const float* __restrict__ bhh2,
              const float* __restrict__ Wproj, const float* __restrict__ bproj,
              float* __restrict__ out)
{
    // frag-unit layout: frag index = slab*64 + kg*16 + (col ^ (kg<<1)); 16B per frag
    __shared__ half8 XA[CT * 4 * 16];   // 16 KB: x chunk   (slab = tt)
    __shared__ half8 H1[2 * 4 * 16];    // 2 KB             (slab = parity)
    __shared__ half8 H2[2 * 4 * 16];    // 2 KB
    __shared__ float HF[16 * 33];
    __shared__ float WPs[16 * 33];
    __shared__ float BPs[16];

    const int tid  = threadIdx.x;
    const int wv   = tid >> 6;        // 0..15
    const int Lly  = wv >> 3;         // 0: L1 waves, 1: L2 waves
    const int t    = wv & 7;          // M-tile (units t*4..t*4+3)
    const int l    = tid & 63;
    const int colB = l & 15;          // batch (B col / A row / D col)
    const int g    = l >> 4;          // k-group; D row group -> lane's unit = t*4+g

    // ---- persistent fp16 register weights (A-frags), unit-major reorder, pre-scaled ----
    half8 Wi, Wr;
    f32x4 bias;
    {
        const float* WI = Lly ? Wih2 : Wih1;
        const float* WH = Lly ? Whh2 : Whh1;
        const float* BI = Lly ? bih2 : bih1;
        const float* BH = Lly ? bhh2 : bhh1;
        const int q = colB & 3;
        const int R = q * 32 + t * 4 + (colB >> 2);
        const float sw = ((q == 2) ? -2.0f : -1.0f) * LOG2E;
#pragma unroll
        for (int e = 0; e < 8; ++e) {
            Wi[e] = (_Float16)(WI[R * 32 + g * 8 + e] * sw);
            Wr[e] = (_Float16)(WH[R * 32 + g * 8 + e] * sw);
        }
#pragma unroll
        for (int qq = 0; qq < 4; ++qq) {
            const int Rb = qq * 32 + t * 4 + g;
            bias[qq] = (((qq == 2) ? -2.0f : -1.0f) * LOG2E) * (BI[Rb] + BH[Rb]);
        }
    }

    for (int i = tid; i < 16 * 32; i += 1024) WPs[(i >> 5) * 33 + (i & 31)] = Wproj[i];
    if (tid < 16) BPs[tid] = bproj[tid];
    {   // zero h state
        ushort* z1 = (ushort*)H1;
        ushort* z2 = (ushort*)H2;
        for (int i = tid; i < 2 * 4 * 16 * 8; i += 1024) { z1[i] = 0; z2[i] = 0; }
    }

    const size_t bglob = (size_t)blockIdx.x * 16;

    // lane's read-frag base (kg = g) and h-write scalar index
    const int fbase = g * 16 + (colB ^ (g << 1));          // + slab*64
    const int kgw   = t >> 1;
    const int hbw   = (kgw * 16 + (colB ^ (kgw << 1))) * 8 + (t & 1) * 4 + g;  // + par*512
    const int unit  = t * 4 + g;

    // x staging: thread -> (step st, batch sb, k-group kg); 32B global load, 16B LDS write
    const int kg = tid & 3;
    const int sb = (tid >> 2) & 15;
    const int st = tid >> 6;   // 0..15
    const float* xsrc = x + ((bglob + sb) * TSTEPS + st) * 32 + kg * 8;
    const int xslot = st * 64 + kg * 16 + (sb ^ (kg << 1));

    float4 xv0 = ((const float4*)xsrc)[0], xv1 = ((const float4*)xsrc)[1];

    float c = 0.f;     // lane's cell state (L1 or L2 per wave role)
    f32x4 pX;          // L1: precomputed bias + x-part for current step

    for (int t0 = 0; t0 < TSTEPS; t0 += CT) {
        // ---- write prefetched x chunk (fp16), prefetch next ----
        {
            half8 hv;
#pragma unroll
            for (int e = 0; e < 4; ++e) { hv[e] = (_Float16)xv0[e]; hv[4 + e] = (_Float16)xv1[e]; }
            XA[xslot] = hv;
        }
        if (t0 + CT < TSTEPS) {
            const float4* p = (const float4*)(xsrc + (size_t)(t0 + CT) * 32);
            xv0 = p[0]; xv1 = p[1];
        }
        BAR_LGKM();        // XA ready; prefetch loads stay in flight (no vmcnt drain)

        if (Lly == 0) {    // pX for tt=0 of this chunk
            pX = bias;
            pX = MFMA_F16(Wi, XA[0 * 64 + fbase], pX);
        }

#pragma unroll 4
        for (int tt = 0; tt < CT; ++tt) {
            const int i = t0 + tt, par = i & 1, parn = par ^ 1;

            if (Lly == 0) {
                // ---- L1 step i: chain = 1 MFMA after the h1 read ----
                const half8 hf = H1[parn * 64 + fbase];
                f32x4 a = pX;
                a = MFMA_F16(Wr, hf, a);
                if (tt < CT - 1) {            // precompute pX for step tt+1 (XA only)
                    pX = bias;
                    pX = MFMA_F16(Wi, XA[(tt + 1) * 64 + fbase], pX);
                }
                const float h = act_fused(a, c);
                ((_Float16*)H1)[par * 512 + hbw] = (_Float16)h;
            } else {
                // ---- L2 step i-1: two parallel 1-chains, merged ----
                const half8 hf = H1[parn * 64 + fbase];
                const half8 Hf = H2[par * 64 + fbase];
                f32x4 e_ = bias;
                f32x4 f_ = {0.f, 0.f, 0.f, 0.f};
                e_ = MFMA_F16(Wi, hf, e_);
                f_ = MFMA_F16(Wr, Hf, f_);
                if (i > 0) {
                    const float h = act_fused(e_ + f_, c);
                    ((_Float16*)H2)[parn * 512 + hbw] = (_Float16)h;
                }
            }
            BAR_LGKM();    // the ONE barrier per step (lgkm-only)
        }
    }

    // ---- epilogue: L2 step 511 from H1[1] (h1(511)) and H2[0] (h2(510)) ----
    if (Lly == 1) {
        const half8 hf = H1[1 * 64 + fbase];
        const half8 Hf = H2[0 * 64 + fbase];
        f32x4 e_ = bias;
        f32x4 f_ = {0.f, 0.f, 0.f, 0.f};
        e_ = MFMA_F16(Wi, hf, e_);
        f_ = MFMA_F16(Wr, Hf, f_);
        HF[colB * 33 + unit] = act_fused(e_ + f_, c);
    }
    __syncthreads();

    // ---- projection: out[b][m] ----
    if (tid < 256) {
        const int b = tid >> 4, m = tid & 15;
        float a = BPs[m];
        const float* hp = &HF[b * 33];
        const float* wp = &WPs[m * 33];
#pragma unroll
        for (int k = 0; k < 32; ++k) a = fmaf(hp[k], wp[k], a);
        out[(bglob + b) * 16 + m] = a;
    }
}

extern "C" void kernel_launch(void* const* d_in, const int* in_sizes, int n_in,
                              void* d_out, int out_size, void* d_ws, size_t ws_size,
                              hipStream_t stream) {
    const float* x     = (const float*)d_in[0];
    const float* Wih1  = (const float*)d_in[1];
    const float* Whh1  = (const float*)d_in[2];
    const float* bih1  = (const float*)d_in[3];
    const float* bhh1  = (const float*)d_in[4];
    const float* Wih2  = (const float*)d_in[5];
    const float* Whh2  = (const float*)d_in[6];
    const float* bih2  = (const float*)d_in[7];
    const float* bhh2  = (const float*)d_in[8];
    const float* Wproj = (const float*)d_in[9];
    const float* bproj = (const float*)d_in[10];
    float* out = (float*)d_out;

    dim3 grid(256), block(1024);
    lstm2_v9<<<grid, block, 0, stream>>>(x, Wih1, Whh1, bih1, bhh1,
                                         Wih2, Whh2, bih2, bhh2,
                                         Wproj, bproj, out);
}

// Round 10
// 192.001 us; speedup vs baseline: 1.0095x; 1.0095x over previous
//
#include <hip/hip_runtime.h>

// Fused 2-layer LSTM (B=4096, T=512, I=H=32) + projection — PLAIN FP16 MFMA, 16 waves.
// FINAL (v8 revert, measured best 192 us): v6 structure + fused activations.
//   i*g      = (1-y) / ((1+xi)(1+y)),  xi=2^zi^, y=2^yg^ (g pre-scaled by -2log2e)
//   o*tanh(c)= (1-u) / ((1+xo)(1+u)),  u=2^(-2log2e*c)
// -> 5 exp2 + 3 rcp = 8 trans/cell. fp32 accumulate; error below harness floor.
//
// Structure: grid 256 x 1024 thr = 16 waves (4/SIMD). Waves 0-7: L1 M-tile t=wv (units
// t*4..t*4+3); waves 8-15: L2 tile t=wv-8. Layer-pipelined: iter i computes L1 step i and
// L2 step i-1; 1 barrier/iter. Lane owns ONE cell (unit t*4+(l>>4), batch l&15): D regs =
// (i,f,g,o) -> lane-local update. L1: pX = bias + MFMA(Wi, x(t)) prefetched a step ahead.
// L2: e = bias+MFMA(Wi,h1) || f = MFMA(Wr,h2), merged by v_add.
// Weights fp16 in registers, pre-scaled by -log2e (i,f,o) / -2log2e (g).
//
// Refuted alternatives (kept for the record): v5 fat-waves (-15%, occupancy), v7 skew-2
// (-4%), v9 lgkm-only barrier (0%). Stall is intrinsic: post-barrier LDS latency + dep
// MFMA + act chain + 16-wave barrier fan-in of an all-to-all recurrence.
//
// Buffers: H1 slot i&1 = h1(i); L1 reads H1[(i-1)&1]; L2 reads H1[(i-1)&1] and H2 slot
// (i-2)&1, writes H2[(i-1)&1]. All cross-iter hazards separated by the end-of-iter
// barrier. i=0: L2 commit guarded. Epilogue: L2 computes step 511 from H1[1], H2[0].

typedef __attribute__((ext_vector_type(4))) float f32x4;
typedef _Float16 half8 __attribute__((ext_vector_type(8)));

#define MFMA_F16(a, b, c) __builtin_amdgcn_mfma_f32_16x16x32_f16(a, b, c, 0, 0, 0)

namespace {
constexpr int TSTEPS = 512;
constexpr int CT     = 16;
constexpr float LOG2E = 1.4426950408889634f;

// acc = (zi^, zf^, yg^, zo^): pre-scaled preacts (-log2e*z for i,f,o; -2log2e*z for g).
// Fused-rcp gate evaluation; updates c, returns h. 5 exp2 + 3 rcp.
__device__ __forceinline__ float act_fused(const f32x4 acc, float& c) {
    const float xi = __builtin_amdgcn_exp2f(acc[0]);
    const float xf = __builtin_amdgcn_exp2f(acc[1]);
    const float y  = __builtin_amdgcn_exp2f(acc[2]);
    const float xo = __builtin_amdgcn_exp2f(acc[3]);
    const float fv = __builtin_amdgcn_rcpf(1.0f + xf);                       // sigma(zf)
    const float ig = (1.0f - y) * __builtin_amdgcn_rcpf((1.0f + xi) * (1.0f + y));
    const float cc = fmaf(fv, c, ig);
    c = cc;
    const float u  = __builtin_amdgcn_exp2f(cc * (-2.0f * LOG2E));
    return (1.0f - u) * __builtin_amdgcn_rcpf((1.0f + xo) * (1.0f + u));    // o*tanh(c)
}
}  // namespace

__global__ __launch_bounds__(1024, 1)
void lstm2_v8f(const float* __restrict__ x,
               const float* __restrict__ Wih1, const float* __restrict__ Whh1,
               const float* __restrict__ bih1, const float* __restrict__ bhh1,
               const float* __restrict__ Wih2, const float* __restrict__ Whh2,
               const float* __restrict__ bih2, const float* __restrict__ bhh2,
               const float* __restrict__ Wproj, const float* __restrict__ bproj,
               float* __restrict__ out)
{
    // frag-unit layout: frag index = slab*64 + kg*16 + (col ^ (kg<<1)); 16B per frag
    __shared__ half8 XA[CT * 4 * 16];   // 16 KB: x chunk   (slab = tt)
    __shared__ half8 H1[2 * 4 * 16];    // 2 KB             (slab = parity)
    __shared__ half8 H2[2 * 4 * 16];    // 2 KB
    __shared__ float HF[16 * 33];
    __shared__ float WPs[16 * 33];
    __shared__ float BPs[16];

    const int tid  = threadIdx.x;
    const int wv   = tid >> 6;        // 0..15
    const int Lly  = wv >> 3;         // 0: L1 waves, 1: L2 waves
    const int t    = wv & 7;          // M-tile (units t*4..t*4+3)
    const int l    = tid & 63;
    const int colB = l & 15;          // batch (B col / A row / D col)
    const int g    = l >> 4;          // k-group; D row group -> lane's unit = t*4+g

    // ---- persistent fp16 register weights (A-frags), unit-major reorder, pre-scaled ----
    half8 Wi, Wr;
    f32x4 bias;
    {
        const float* WI = Lly ? Wih2 : Wih1;
        const float* WH = Lly ? Whh2 : Whh1;
        const float* BI = Lly ? bih2 : bih1;
        const float* BH = Lly ? bhh2 : bhh1;
        const int q = colB & 3;
        const int R = q * 32 + t * 4 + (colB >> 2);
        const float sw = ((q == 2) ? -2.0f : -1.0f) * LOG2E;
#pragma unroll
        for (int e = 0; e < 8; ++e) {
            Wi[e] = (_Float16)(WI[R * 32 + g * 8 + e] * sw);
            Wr[e] = (_Float16)(WH[R * 32 + g * 8 + e] * sw);
        }
#pragma unroll
        for (int qq = 0; qq < 4; ++qq) {
            const int Rb = qq * 32 + t * 4 + g;
            bias[qq] = (((qq == 2) ? -2.0f : -1.0f) * LOG2E) * (BI[Rb] + BH[Rb]);
        }
    }

    for (int i = tid; i < 16 * 32; i += 1024) WPs[(i >> 5) * 33 + (i & 31)] = Wproj[i];
    if (tid < 16) BPs[tid] = bproj[tid];
    {   // zero h state
        ushort* z1 = (ushort*)H1;
        ushort* z2 = (ushort*)H2;
        for (int i = tid; i < 2 * 4 * 16 * 8; i += 1024) { z1[i] = 0; z2[i] = 0; }
    }

    const size_t bglob = (size_t)blockIdx.x * 16;

    // lane's read-frag base (kg = g) and h-write scalar index
    const int fbase = g * 16 + (colB ^ (g << 1));          // + slab*64
    const int kgw   = t >> 1;
    const int hbw   = (kgw * 16 + (colB ^ (kgw << 1))) * 8 + (t & 1) * 4 + g;  // + par*512
    const int unit  = t * 4 + g;

    // x staging: thread -> (step st, batch sb, k-group kg); 32B global load, 16B LDS write
    const int kg = tid & 3;
    const int sb = (tid >> 2) & 15;
    const int st = tid >> 6;   // 0..15
    const float* xsrc = x + ((bglob + sb) * TSTEPS + st) * 32 + kg * 8;
    const int xslot = st * 64 + kg * 16 + (sb ^ (kg << 1));

    float4 xv0 = ((const float4*)xsrc)[0], xv1 = ((const float4*)xsrc)[1];

    float c = 0.f;     // lane's cell state (L1 or L2 per wave role)
    f32x4 pX;          // L1: precomputed bias + x-part for current step

    for (int t0 = 0; t0 < TSTEPS; t0 += CT) {
        // ---- write prefetched x chunk (fp16), prefetch next ----
        {
            half8 hv;
#pragma unroll
            for (int e = 0; e < 4; ++e) { hv[e] = (_Float16)xv0[e]; hv[4 + e] = (_Float16)xv1[e]; }
            XA[xslot] = hv;
        }
        if (t0 + CT < TSTEPS) {
            const float4* p = (const float4*)(xsrc + (size_t)(t0 + CT) * 32);
            xv0 = p[0]; xv1 = p[1];
        }
        __syncthreads();   // XA ready (also orders vs. prior chunk's reads)

        if (Lly == 0) {    // pX for tt=0 of this chunk
            pX = bias;
            pX = MFMA_F16(Wi, XA[0 * 64 + fbase], pX);
        }

#pragma unroll 2
        for (int tt = 0; tt < CT; ++tt) {
            const int i = t0 + tt, par = i & 1, parn = par ^ 1;

            if (Lly == 0) {
                // ---- L1 step i: chain = 1 MFMA after the h1 read ----
                const half8 hf = H1[parn * 64 + fbase];
                f32x4 a = pX;
                a = MFMA_F16(Wr, hf, a);
                if (tt < CT - 1) {            // precompute pX for step tt+1 (XA only)
                    pX = bias;
                    pX = MFMA_F16(Wi, XA[(tt + 1) * 64 + fbase], pX);
                }
                const float h = act_fused(a, c);
                ((_Float16*)H1)[par * 512 + hbw] = (_Float16)h;
            } else {
                // ---- L2 step i-1: two parallel 1-chains, merged ----
                const half8 hf = H1[parn * 64 + fbase];
                const half8 Hf = H2[par * 64 + fbase];
                f32x4 e_ = bias;
                f32x4 f_ = {0.f, 0.f, 0.f, 0.f};
                e_ = MFMA_F16(Wi, hf, e_);
                f_ = MFMA_F16(Wr, Hf, f_);
                if (i > 0) {
                    const float h = act_fused(e_ + f_, c);
                    ((_Float16*)H2)[parn * 512 + hbw] = (_Float16)h;
                }
            }
            __syncthreads();   // the ONE barrier per step
        }
    }

    // ---- epilogue: L2 step 511 from H1[1] (h1(511)) and H2[0] (h2(510)) ----
    if (Lly == 1) {
        const half8 hf = H1[1 * 64 + fbase];
        const half8 Hf = H2[0 * 64 + fbase];
        f32x4 e_ = bias;
        f32x4 f_ = {0.f, 0.f, 0.f, 0.f};
        e_ = MFMA_F16(Wi, hf, e_);
        f_ = MFMA_F16(Wr, Hf, f_);
        HF[colB * 33 + unit] = act_fused(e_ + f_, c);
    }
    __syncthreads();

    // ---- projection: out[b][m] ----
    if (tid < 256) {
        const int b = tid >> 4, m = tid & 15;
        float a = BPs[m];
        const float* hp = &HF[b * 33];
        const float* wp = &WPs[m * 33];
#pragma unroll
        for (int k = 0; k < 32; ++k) a = fmaf(hp[k], wp[k], a);
        out[(bglob + b) * 16 + m] = a;
    }
}

extern "C" void kernel_launch(void* const* d_in, const int* in_sizes, int n_in,
                              void* d_out, int out_size, void* d_ws, size_t ws_size,
                              hipStream_t stream) {
    const float* x     = (const float*)d_in[0];
    const float* Wih1  = (const float*)d_in[1];
    const float* Whh1  = (const float*)d_in[2];
    const float* bih1  = (const float*)d_in[3];
    const float* bhh1  = (const float*)d_in[4];
    const float* Wih2  = (const float*)d_in[5];
    const float* Whh2  = (const float*)d_in[6];
    const float* bih2  = (const float*)d_in[7];
    const float* bhh2  = (const float*)d_in[8];
    const float* Wproj = (const float*)d_in[9];
    const float* bproj = (const float*)d_in[10];
    float* out = (float*)d_out;

    dim3 grid(256), block(1024);
    lstm2_v8f<<<grid, block, 0, stream>>>(x, Wih1, Whh1, bih1, bhh1,
                                          Wih2, Whh2, bih2, bhh2,
                                          Wproj, bproj, out);
}